// Round 10
// baseline (131.466 us; speedup 1.0000x reference)
//
#include <hip/hip_runtime.h>
#include <stdint.h>

// VectorQuantizer on MI355X (gfx950), fp32 exact path, round 10.
// R9 got occupancy (8 waves/SIMD, 58% busy) but reintroduced the R5 defect:
// ds_read(x) and s_load(w) share lgkmcnt; OOO SMEM forces conservative waits
// that drain w prefetches. R6 proved global-x (vmcnt) decouples the pipes but
// ran at 36% occupancy. This round combines them: R9's 8-wave blocking +
// in-LDS merge + fused epilogue, with x fed from a float4-granular transposed
// global layout xT4[d4][n] (2 dwordx4 loads per d8-iter, vmcnt domain, zero
// LDS in the hot loop). Fallback to the R9 kernel if ws is too small.

#define N_PTS 65536
#define DDIM 64
#define KCODES 512

// ws big layout: xT4 16777216 B @ 0, wT 131072 B @ 16777216,
//                wsq 2048 B @ 16908288 -> need 16910336 B (R6-proven)

__global__ void vq_prep2(const float* __restrict__ x_in,
                         const float* __restrict__ w,
                         float4* __restrict__ xT4,  // [16][65536] float4
                         float* __restrict__ wT, float* __restrict__ wsq,
                         float* __restrict__ loss_out) {
  __shared__ float tile[64][65];  // tile[point][dim], +1 pad
  const int b = blockIdx.x;
  const int t = threadIdx.x;
  if (b < 1024) {
    const float4* src = (const float4*)(x_in + (size_t)b * 4096);
#pragma unroll
    for (int p = 0; p < 4; ++p) {
      int e = p * 1024 + t * 4;
      float4 v = src[p * 256 + t];          // coalesced 16B
      int pt = e >> 6, d = e & 63;
      tile[pt][d] = v.x; tile[pt][d + 1] = v.y;
      tile[pt][d + 2] = v.z; tile[pt][d + 3] = v.w;
    }
    __syncthreads();
    // write xT4[d4][n] = x[n][4*d4 .. +3], coalesced across n
#pragma unroll
    for (int p = 0; p < 4; ++p) {
      int idx = p * 256 + t;               // 0..1023 = d4*64 + nl
      int d4 = idx >> 6, nl = idx & 63;
      float4 v = make_float4(tile[nl][d4 * 4], tile[nl][d4 * 4 + 1],
                             tile[nl][d4 * 4 + 2], tile[nl][d4 * 4 + 3]);
      xT4[((size_t)d4 << 16) + (b << 6) + nl] = v;
    }
  } else {
    int g = (b - 1024) * 256 + t;  // 0..32767 over D*K
    int d = g >> 9, k = g & 511;
    wT[k * DDIM + d] = w[g];
    if (g < KCODES) {
      float s = 0.f;
      for (int dd = 0; dd < DDIM; ++dd) {
        float tv = w[dd * KCODES + g];
        s = fmaf(tv, tv, s);
      }
      wsq[g] = s;
    }
    if (g == 0) *loss_out = 0.f;   // d_out is poisoned each launch
  }
}

__global__ __launch_bounds__(512, 8)
void vq_main2(const float4* __restrict__ xT4, const float* __restrict__ w,
              const float* __restrict__ wT, const float* __restrict__ wsq,
              float* __restrict__ out_q, float* __restrict__ out_idx,
              float* __restrict__ loss_out) {
  __shared__ unsigned long long sm_key[8][64];  // per-wave candidate keys
  __shared__ unsigned int sm_idx[64];
  __shared__ float sm_sx[64];
  __shared__ float sm_loss[64];

  const int t = threadIdx.x;
  const int pb = blockIdx.x;                              // 1024 blocks, 64 pts
  const int wv = __builtin_amdgcn_readfirstlane(t >> 6);  // wave id 0..7 (SGPR)
  const int lane = t & 63;                                // lane = point id
  const int n = (pb << 6) | lane;                         // global point id
  const int kbase = wv << 6;                              // wave's 64 codes

  const float4* xp = xT4 + n;   // + d4*65536 per 4-dim group, coalesced

  float best = 3.0e38f;
  int bidx = 0;
  float sx = 0.f;

#pragma unroll 1
  for (int kb = 0; kb < 2; ++kb) {       // 2 x 32-code windows (R6/R9 codegen)
    const int k0 = kbase + (kb << 5);
    const float* wp = w + k0;            // SGPR-rooted -> s_load promotion
    float acc[32];
#pragma unroll
    for (int c = 0; c < 32; ++c) acc[c] = 0.f;

#pragma unroll 1
    for (int d8 = 0; d8 < 8; ++d8) {
      // x feed: 2 coalesced dwordx4 from global (vmcnt domain, decoupled
      // from the s_load lgkmcnt stream)
      float4 a = xp[(size_t)(d8 * 2) << 16];
      float4 b = xp[(size_t)(d8 * 2 + 1) << 16];
      float xv[8] = {a.x, a.y, a.z, a.w, b.x, b.y, b.z, b.w};
      if (wv == 0 && kb == 0) {  // wave-uniform: ||x||^2 once per point
#pragma unroll
        for (int dd = 0; dd < 8; ++dd) sx = fmaf(xv[dd], xv[dd], sx);
      }
#pragma unroll
      for (int dd = 0; dd < 8; ++dd) {
        const float* wd = wp + (((d8 << 3) + dd) << 9);  // w[d][k0..k0+31]
#pragma unroll
        for (int c = 0; c < 32; ++c)
          acc[c] = fmaf(wd[c], xv[dd], acc[c]);  // sgpr * vgpr fmac
      }
    }
#pragma unroll
    for (int c = 0; c < 32; ++c) {
      float dist = fmaf(acc[c], -2.0f, wsq[k0 + c]);
      if (dist < best) { best = dist; bidx = k0 + c; }  // strict <: first-min
    }
  }

  // sortable-float pack, idx in low bits -> exact ties pick lowest index
  unsigned int ub = __float_as_uint(best);
  ub = (ub & 0x80000000u) ? ~ub : (ub | 0x80000000u);
  sm_key[wv][lane] =
      ((unsigned long long)ub << 32) | (unsigned long long)(unsigned int)bidx;
  if (wv == 0) sm_sx[lane] = sx;
  __syncthreads();

  // ---- merge the 8 per-wave candidates for each of the 64 points ----
  if (t < 64) {
    unsigned long long k = sm_key[0][t];
#pragma unroll
    for (int wi = 1; wi < 8; ++wi) {
      unsigned long long k2 = sm_key[wi][t];
      k = k2 < k ? k2 : k;
    }
    unsigned int idx = (unsigned int)k;
    sm_idx[t] = idx;
    out_idx[((size_t)pb << 6) + t] = (float)idx;
    unsigned int u = (unsigned int)(k >> 32);
    u = (u & 0x80000000u) ? (u & 0x7FFFFFFFu) : ~u;
    // ||x-q||^2 = ||x||^2 + (||q||^2 - 2 x.q), pre-scaled by 1.25/(N*D)
    sm_loss[t] = (__uint_as_float(u) + sm_sx[t]) * (1.25f / 4194304.0f);
  }
  __syncthreads();

  // ---- epilogue: gather code rows, coalesced 64x64 out tile ----
  float4* dst = (float4*)(out_q + (size_t)pb * 4096);
#pragma unroll
  for (int i = 0; i < 2; ++i) {
    int e4 = i * 512 + t;
    int p2 = e4 >> 4, d4 = e4 & 15;
    unsigned int idx = sm_idx[p2];                            // LDS broadcast
    dst[e4] = ((const float4*)(wT + (size_t)idx * DDIM))[d4]; // L2-hot
  }

  // block loss partial -> single atomic (1024 adds total)
  if (t < 64) {
    float s = sm_loss[t];
#pragma unroll
    for (int off = 32; off > 0; off >>= 1) s += __shfl_down(s, off);
    if (t == 0) atomicAdd(loss_out, s);
  }
}

// ---------------- fallback path (R9 kernels, proven 61us) ----------------

__global__ void vq_prep(const float* __restrict__ w, float* __restrict__ wT,
                        float* __restrict__ wsq, float* __restrict__ loss_out) {
  int g = blockIdx.x * 256 + threadIdx.x;
  int d = g >> 9, k = g & 511;
  wT[k * DDIM + d] = w[g];
  if (g < KCODES) {
    float s = 0.f;
    for (int dd = 0; dd < DDIM; ++dd) {
      float t = w[dd * KCODES + g];
      s = fmaf(t, t, s);
    }
    wsq[g] = s;
  }
  if (g == 0) *loss_out = 0.f;
}

__global__ __launch_bounds__(512, 8)
void vq_main(const float* __restrict__ x_in, const float* __restrict__ w,
             const float* __restrict__ wT, const float* __restrict__ wsq,
             float* __restrict__ out_q, float* __restrict__ out_idx,
             float* __restrict__ loss_out) {
  __shared__ float xs[DDIM][65];
  __shared__ unsigned long long sm_key[8][64];
  __shared__ unsigned int sm_idx[64];
  __shared__ float sm_sx[64];
  __shared__ float sm_loss[64];

  const int t = threadIdx.x;
  const int pb = blockIdx.x;
  const int wv = __builtin_amdgcn_readfirstlane(t >> 6);
  const int lane = t & 63;

  {
    const float4* src = (const float4*)(x_in + (size_t)pb * 4096);
#pragma unroll
    for (int i = 0; i < 2; ++i) {
      int e4 = i * 512 + t;
      float4 v = src[e4];
      int e = e4 << 2;
      int pt = e >> 6, d = e & 63;
      xs[d][pt] = v.x; xs[d + 1][pt] = v.y;
      xs[d + 2][pt] = v.z; xs[d + 3][pt] = v.w;
    }
  }
  __syncthreads();

  const int kbase = wv << 6;
  float best = 3.0e38f;
  int bidx = 0;
  float sx = 0.f;

#pragma unroll 1
  for (int kb = 0; kb < 2; ++kb) {
    const int k0 = kbase + (kb << 5);
    const float* wp = w + k0;
    float acc[32];
#pragma unroll
    for (int c = 0; c < 32; ++c) acc[c] = 0.f;
#pragma unroll 1
    for (int d8 = 0; d8 < 8; ++d8) {
      float xv[8];
#pragma unroll
      for (int dd = 0; dd < 8; ++dd) xv[dd] = xs[(d8 << 3) + dd][lane];
      if (wv == 0 && kb == 0) {
#pragma unroll
        for (int dd = 0; dd < 8; ++dd) sx = fmaf(xv[dd], xv[dd], sx);
      }
#pragma unroll
      for (int dd = 0; dd < 8; ++dd) {
        const float* wd = wp + (((d8 << 3) + dd) << 9);
#pragma unroll
        for (int c = 0; c < 32; ++c)
          acc[c] = fmaf(wd[c], xv[dd], acc[c]);
      }
    }
#pragma unroll
    for (int c = 0; c < 32; ++c) {
      float dist = fmaf(acc[c], -2.0f, wsq[k0 + c]);
      if (dist < best) { best = dist; bidx = k0 + c; }
    }
  }

  unsigned int ub = __float_as_uint(best);
  ub = (ub & 0x80000000u) ? ~ub : (ub | 0x80000000u);
  sm_key[wv][lane] =
      ((unsigned long long)ub << 32) | (unsigned long long)(unsigned int)bidx;
  if (wv == 0) sm_sx[lane] = sx;
  __syncthreads();

  if (t < 64) {
    unsigned long long k = sm_key[0][t];
#pragma unroll
    for (int wi = 1; wi < 8; ++wi) {
      unsigned long long k2 = sm_key[wi][t];
      k = k2 < k ? k2 : k;
    }
    unsigned int idx = (unsigned int)k;
    sm_idx[t] = idx;
    out_idx[((size_t)pb << 6) + t] = (float)idx;
    unsigned int u = (unsigned int)(k >> 32);
    u = (u & 0x80000000u) ? (u & 0x7FFFFFFFu) : ~u;
    sm_loss[t] = (__uint_as_float(u) + sm_sx[t]) * (1.25f / 4194304.0f);
  }
  __syncthreads();

  float4* dst = (float4*)(out_q + (size_t)pb * 4096);
#pragma unroll
  for (int i = 0; i < 2; ++i) {
    int e4 = i * 512 + t;
    int p2 = e4 >> 4, d4 = e4 & 15;
    unsigned int idx = sm_idx[p2];
    dst[e4] = ((const float4*)(wT + (size_t)idx * DDIM))[d4];
  }

  if (t < 64) {
    float s = sm_loss[t];
#pragma unroll
    for (int off = 32; off > 0; off >>= 1) s += __shfl_down(s, off);
    if (t == 0) atomicAdd(loss_out, s);
  }
}

extern "C" void kernel_launch(void* const* d_in, const int* in_sizes, int n_in,
                              void* d_out, int out_size, void* d_ws, size_t ws_size,
                              hipStream_t stream) {
  const float* x = (const float*)d_in[0];  // (64,32,32,64) fp32
  const float* w = (const float*)d_in[1];  // (64,512) fp32

  float* out_q = (float*)d_out;            // 4194304 floats
  float* out_idx = out_q + 4194304;        // 65536 floats (indices)
  float* loss_out = out_q + 4259840;       // 1 float

  char* ws = (char*)d_ws;
  if (ws_size >= 16910336) {
    float4* xT4 = (float4*)(ws);
    float* wT = (float*)(ws + 16777216);
    float* wsq = (float*)(ws + 16908288);
    vq_prep2<<<1152, 256, 0, stream>>>(x, w, xT4, wT, wsq, loss_out);
    vq_main2<<<1024, 512, 0, stream>>>(xT4, w, wT, wsq, out_q, out_idx,
                                       loss_out);
  } else {
    float* wT = (float*)(ws);
    float* wsq = (float*)(ws + 131072);
    vq_prep<<<128, 256, 0, stream>>>(w, wT, wsq, loss_out);
    vq_main<<<1024, 512, 0, stream>>>(x, w, wT, wsq, out_q, out_idx,
                                      loss_out);
  }
}

// Round 11
// 113.178 us; speedup vs baseline: 1.1616x; 1.1616x over previous
//
#include <hip/hip_runtime.h>
#include <stdint.h>

// VectorQuantizer on MI355X (gfx950), round 11: bf16x3 split-GEMM on MFMA.
// fp32 scalar-FMA structure saturates at ~60% busy (R4-R10): wave-uniform w
// needs 128B/64cy vs ~250cy SMEM latency -> SGPR prefetch can't cover.
// Matrix pipe is idle. S = x.w computed as 6 bf16 MFMA products chained into
// one fp32 accumulator (x1w1,x1w2,x2w1,x2w2,x1w3,x3w1): method error ~2^-27
// rel, below the fp32-vs-np noise the harness already accepts.
// prep: split x -> A-fragment bf16 arrays (XA1,XA2 in d_out quantized region,
//       XA3 in ws), split w -> B-fragment WB (192KB, ws), + wT/wsq/xsq.
// main: 512 blocks x 4 waves; wave = 32 pts; per phase stage 48KB of WB in
//       LDS, 24 MFMA per ct (2 a-sets x 12), per-lane argmin on C layout
//       (pt = quad*4+reg, code = col), shfl_xor key reduce, block merge.
// gather: separate kernel (overwrites XA1/XA2 region after main consumed).

#define DDIM 64
#define KCODES 512

typedef __bf16 bf16x8 __attribute__((ext_vector_type(8)));
typedef float f32x4 __attribute__((ext_vector_type(4)));

// ws layout (bytes): XA3 @0 (8388608), WB @8388608 (196608),
//   wT @8585216 (131072), xsq @8716288 (262144), wsq @8978432 (2048)
//   -> need 8980480 (R6/R10 proved ws >= 16.9MB, so this fits)

__device__ __forceinline__ void split3(float f, __bf16& h1, __bf16& h2,
                                       __bf16& h3) {
  h1 = (__bf16)f;
  float r1 = f - (float)h1;   // exact (Sterbenz)
  h2 = (__bf16)r1;
  float r2 = r1 - (float)h2;  // exact
  h3 = (__bf16)r2;            // residual beyond h3 ~ 2^-27 |f|
}

__global__ void vq_prep_m(const float* __restrict__ x_in,
                          const float* __restrict__ w,
                          bf16x8* __restrict__ xa1, bf16x8* __restrict__ xa2,
                          bf16x8* __restrict__ xa3, bf16x8* __restrict__ wb,
                          float* __restrict__ wT, float* __restrict__ wsq,
                          float* __restrict__ xsq,
                          float* __restrict__ loss_out) {
  __shared__ float xs[64][65];
  const int b = blockIdx.x, t = threadIdx.x;
  if (b < 1024) {
    // ---- x split: 64 pts/block -> A-fragment layout ----
    const float4* src = (const float4*)(x_in + (size_t)b * 4096);
#pragma unroll
    for (int i = 0; i < 4; ++i) {
      float4 v = src[i * 256 + t];            // coalesced
      int e = (i * 256 + t) * 4;
      int pt = e >> 6, d = e & 63;
      xs[pt][d] = v.x; xs[pt][d + 1] = v.y;
      xs[pt][d + 2] = v.z; xs[pt][d + 3] = v.w;
    }
    __syncthreads();
    const int grp = t >> 6, L = t & 63, quad = L >> 4, col = L & 15;
    const int ptl = grp * 16 + col;
    const int nblk = b * 4 + grp;             // 16-pt fragment row group
    float ssq = 0.f;
#pragma unroll
    for (int h = 0; h < 2; ++h) {
      bf16x8 v1, v2, v3;
#pragma unroll
      for (int j = 0; j < 8; ++j) {
        // A[m=col][k=quad*8+j+32h]  (m120-verified A-operand layout)
        float f = xs[ptl][quad * 8 + 32 * h + j];
        ssq = fmaf(f, f, ssq);
        __bf16 h1, h2, h3; split3(f, h1, h2, h3);
        v1[j] = h1; v2[j] = h2; v3[j] = h3;
      }
      int idx = (nblk * 2 + h) * 64 + L;      // 16B/lane contiguous
      xa1[idx] = v1; xa2[idx] = v2; xa3[idx] = v3;
    }
    ssq += __shfl_xor(ssq, 16, 64);           // combine the 4 quads
    ssq += __shfl_xor(ssq, 32, 64);
    if (quad == 0) xsq[b * 64 + ptl] = ssq;   // fp32-exact ||x||^2
  } else if (b < 1056) {
    // ---- w split: one 16-code tile per block -> B-fragment layout ----
    const int ctg = b - 1024;                 // 0..31
    const int u = t >> 6, L = t & 63, quad = L >> 4, col = L & 15;
    if (u < 2) {
      const int h = u;
      bf16x8 v1, v2, v3;
#pragma unroll
      for (int j = 0; j < 8; ++j) {
        // B[k=quad*8+j+32h][n=ctg*16+col]
        float f = w[(quad * 8 + 32 * h + j) * KCODES + ctg * 16 + col];
        __bf16 h1, h2, h3; split3(f, h1, h2, h3);
        v1[j] = h1; v2[j] = h2; v3[j] = h3;
      }
      int idx = (ctg * 2 + h) * 64 + L;
      wb[idx] = v1; wb[4096 + idx] = v2; wb[8192 + idx] = v3;
    }
  } else {
    // ---- wT / wsq / loss-zero ----
    int g = (b - 1056) * 256 + t;             // 0..32767 over D*K
    int d = g >> 9, k = g & 511;
    wT[k * DDIM + d] = w[g];
    if (g < KCODES) {
      float s = 0.f;
      for (int dd = 0; dd < DDIM; ++dd) {
        float tv = w[dd * KCODES + g];
        s = fmaf(tv, tv, s);
      }
      wsq[g] = s;
    }
    if (g == 0) *loss_out = 0.f;
  }
}

__global__ __launch_bounds__(256, 2)
void vq_mfma(const bf16x8* __restrict__ xa1, const bf16x8* __restrict__ xa2,
             const bf16x8* __restrict__ xa3, const bf16x8* __restrict__ wb,
             const float* __restrict__ wsq, const float* __restrict__ xsq,
             float* __restrict__ out_idx, float* __restrict__ loss_out) {
  __shared__ bf16x8 ldsb[3072];               // 48KB: one 128-code phase
  __shared__ unsigned long long sm_key[128];
  __shared__ float sm_loss[128];

  const int t = threadIdx.x, b = blockIdx.x;  // 512 blocks, 128 pts each
  const int wv = t >> 6, L = t & 63, quad = L >> 4, col = L & 15;
  const int nblk0 = b * 8 + wv * 2;           // wave owns 2 16-pt a-sets

  // a-frags resident all kernel: 2 asets x 3 splits x 2 k-halves = 48 VGPR
  bf16x8 a[2][3][2];
#pragma unroll
  for (int as = 0; as < 2; ++as) {
    int base = (nblk0 + as) * 2;
#pragma unroll
    for (int h = 0; h < 2; ++h) {
      a[as][0][h] = xa1[(base + h) * 64 + L];
      a[as][1][h] = xa2[(base + h) * 64 + L];
      a[as][2][h] = xa3[(base + h) * 64 + L];
    }
  }

  float best[2][4];
  int bidx[2][4];
#pragma unroll
  for (int as = 0; as < 2; ++as)
#pragma unroll
    for (int r = 0; r < 4; ++r) { best[as][r] = 3.0e38f; bidx[as][r] = 0; }

#pragma unroll 1
  for (int ph = 0; ph < 4; ++ph) {
    if (ph) __syncthreads();                  // prev compute done
    // stage 48 chunks (ct,h,s) x 64 lanes of B-frags into LDS
#pragma unroll
    for (int i = 0; i < 12; ++i) {
      int idx = i * 256 + t;
      int chunk = idx >> 6, Ls = idx & 63;    // chunk = ct*6 + h*3 + s
      int ct = chunk / 6, r6 = chunk % 6;
      int h = r6 / 3, s = r6 % 3;
      ldsb[chunk * 64 + Ls] =
          wb[s * 4096 + ((ph * 8 + ct) * 2 + h) * 64 + Ls];
    }
    __syncthreads();
#pragma unroll 1
    for (int ct = 0; ct < 8; ++ct) {
      f32x4 acc0 = {0.f, 0.f, 0.f, 0.f};
      f32x4 acc1 = {0.f, 0.f, 0.f, 0.f};
#pragma unroll
      for (int h = 0; h < 2; ++h) {
        bf16x8 b0 = ldsb[(ct * 6 + h * 3 + 0) * 64 + L];
        bf16x8 b1 = ldsb[(ct * 6 + h * 3 + 1) * 64 + L];
        bf16x8 b2 = ldsb[(ct * 6 + h * 3 + 2) * 64 + L];
        // 6-term split per a-set, all into one fp32 accumulator
        acc0 = __builtin_amdgcn_mfma_f32_16x16x32_bf16(a[0][0][h], b0, acc0, 0, 0, 0);
        acc1 = __builtin_amdgcn_mfma_f32_16x16x32_bf16(a[1][0][h], b0, acc1, 0, 0, 0);
        acc0 = __builtin_amdgcn_mfma_f32_16x16x32_bf16(a[0][0][h], b1, acc0, 0, 0, 0);
        acc1 = __builtin_amdgcn_mfma_f32_16x16x32_bf16(a[1][0][h], b1, acc1, 0, 0, 0);
        acc0 = __builtin_amdgcn_mfma_f32_16x16x32_bf16(a[0][1][h], b0, acc0, 0, 0, 0);
        acc1 = __builtin_amdgcn_mfma_f32_16x16x32_bf16(a[1][1][h], b0, acc1, 0, 0, 0);
        acc0 = __builtin_amdgcn_mfma_f32_16x16x32_bf16(a[0][1][h], b1, acc0, 0, 0, 0);
        acc1 = __builtin_amdgcn_mfma_f32_16x16x32_bf16(a[1][1][h], b1, acc1, 0, 0, 0);
        acc0 = __builtin_amdgcn_mfma_f32_16x16x32_bf16(a[0][0][h], b2, acc0, 0, 0, 0);
        acc1 = __builtin_amdgcn_mfma_f32_16x16x32_bf16(a[1][0][h], b2, acc1, 0, 0, 0);
        acc0 = __builtin_amdgcn_mfma_f32_16x16x32_bf16(a[0][2][h], b0, acc0, 0, 0, 0);
        acc1 = __builtin_amdgcn_mfma_f32_16x16x32_bf16(a[1][2][h], b0, acc1, 0, 0, 0);
      }
      // dist + per-lane argmin; C layout: pt = quad*4 + r, code = col
      int code = ph * 128 + ct * 16 + col;
      float wq = wsq[code];
#pragma unroll
      for (int r = 0; r < 4; ++r) {
        float d0 = fmaf(acc0[r], -2.0f, wq);
        if (d0 < best[0][r]) { best[0][r] = d0; bidx[0][r] = code; }
        float d1 = fmaf(acc1[r], -2.0f, wq);
        if (d1 < best[1][r]) { best[1][r] = d1; bidx[1][r] = code; }
      }
    }
  }

  // cross-lane reduce over the 16 cols (same pts share a quad-segment)
#pragma unroll
  for (int as = 0; as < 2; ++as) {
#pragma unroll
    for (int r = 0; r < 4; ++r) {
      unsigned int ub = __float_as_uint(best[as][r]);
      ub = (ub & 0x80000000u) ? ~ub : (ub | 0x80000000u);
      unsigned long long key = ((unsigned long long)ub << 32) |
                               (unsigned long long)(unsigned int)bidx[as][r];
#pragma unroll
      for (int off = 1; off < 16; off <<= 1) {
        unsigned long long o = __shfl_xor(key, off, 64);
        key = o < key ? o : key;              // ties -> lowest idx
      }
      if (col == 0)
        sm_key[wv * 32 + as * 16 + quad * 4 + r] = key;
    }
  }
  __syncthreads();

  if (t < 128) {
    unsigned long long k = sm_key[t];
    unsigned int idx = (unsigned int)k;
    out_idx[(size_t)b * 128 + t] = (float)idx;
    unsigned int u = (unsigned int)(k >> 32);
    u = (u & 0x80000000u) ? (u & 0x7FFFFFFFu) : ~u;
    // ||x-q||^2 = ||x||^2 + (||q||^2 - 2 x.q), pre-scaled by 1.25/(N*D)
    sm_loss[t] =
        (__uint_as_float(u) + xsq[(size_t)b * 128 + t]) * (1.25f / 4194304.0f);
  }
  __syncthreads();
  if (t < 64) {
    float s = sm_loss[t] + sm_loss[t + 64];
#pragma unroll
    for (int off = 32; off > 0; off >>= 1) s += __shfl_down(s, off);
    if (t == 0) atomicAdd(loss_out, s);       // 512 adds total
  }
}

__global__ void vq_gather(const float* __restrict__ idx_f,
                          const float* __restrict__ wT,
                          float4* __restrict__ out_q) {
  int g4 = blockIdx.x * 256 + threadIdx.x;    // 4096 blocks over N*D/4
  int n = g4 >> 4, d4 = g4 & 15;
  unsigned int idx = (unsigned int)idx_f[n];
  out_q[g4] = ((const float4*)(wT + (size_t)idx * DDIM))[d4];  // L2-hot
}

// ---------------- fallback (R9 kernels, proven) ----------------

__global__ void vq_prep(const float* __restrict__ w, float* __restrict__ wT,
                        float* __restrict__ wsq, float* __restrict__ loss_out) {
  int g = blockIdx.x * 256 + threadIdx.x;
  int d = g >> 9, k = g & 511;
  wT[k * DDIM + d] = w[g];
  if (g < KCODES) {
    float s = 0.f;
    for (int dd = 0; dd < DDIM; ++dd) {
      float t = w[dd * KCODES + g];
      s = fmaf(t, t, s);
    }
    wsq[g] = s;
  }
  if (g == 0) *loss_out = 0.f;
}

__global__ __launch_bounds__(512, 8)
void vq_main(const float* __restrict__ x_in, const float* __restrict__ w,
             const float* __restrict__ wT, const float* __restrict__ wsq,
             float* __restrict__ out_q, float* __restrict__ out_idx,
             float* __restrict__ loss_out) {
  __shared__ float xs[DDIM][65];
  __shared__ unsigned long long sm_key[8][64];
  __shared__ unsigned int sm_idx[64];
  __shared__ float sm_sx[64];
  __shared__ float sm_loss[64];

  const int t = threadIdx.x;
  const int pb = blockIdx.x;
  const int wv = __builtin_amdgcn_readfirstlane(t >> 6);
  const int lane = t & 63;

  {
    const float4* src = (const float4*)(x_in + (size_t)pb * 4096);
#pragma unroll
    for (int i = 0; i < 2; ++i) {
      int e4 = i * 512 + t;
      float4 v = src[e4];
      int e = e4 << 2;
      int pt = e >> 6, d = e & 63;
      xs[d][pt] = v.x; xs[d + 1][pt] = v.y;
      xs[d + 2][pt] = v.z; xs[d + 3][pt] = v.w;
    }
  }
  __syncthreads();

  const int kbase = wv << 6;
  float best = 3.0e38f;
  int bidx = 0;
  float sx = 0.f;

#pragma unroll 1
  for (int kb = 0; kb < 2; ++kb) {
    const int k0 = kbase + (kb << 5);
    const float* wp = w + k0;
    float acc[32];
#pragma unroll
    for (int c = 0; c < 32; ++c) acc[c] = 0.f;
#pragma unroll 1
    for (int d8 = 0; d8 < 8; ++d8) {
      float xv[8];
#pragma unroll
      for (int dd = 0; dd < 8; ++dd) xv[dd] = xs[(d8 << 3) + dd][lane];
      if (wv == 0 && kb == 0) {
#pragma unroll
        for (int dd = 0; dd < 8; ++dd) sx = fmaf(xv[dd], xv[dd], sx);
      }
#pragma unroll
      for (int dd = 0; dd < 8; ++dd) {
        const float* wd = wp + (((d8 << 3) + dd) << 9);
#pragma unroll
        for (int c = 0; c < 32; ++c) acc[c] = fmaf(wd[c], xv[dd], acc[c]);
      }
    }
#pragma unroll
    for (int c = 0; c < 32; ++c) {
      float dist = fmaf(acc[c], -2.0f, wsq[k0 + c]);
      if (dist < best) { best = dist; bidx = k0 + c; }
    }
  }

  unsigned int ub = __float_as_uint(best);
  ub = (ub & 0x80000000u) ? ~ub : (ub | 0x80000000u);
  sm_key[wv][lane] =
      ((unsigned long long)ub << 32) | (unsigned long long)(unsigned int)bidx;
  if (wv == 0) sm_sx[lane] = sx;
  __syncthreads();

  if (t < 64) {
    unsigned long long k = sm_key[0][t];
#pragma unroll
    for (int wi = 1; wi < 8; ++wi) {
      unsigned long long k2 = sm_key[wi][t];
      k = k2 < k ? k2 : k;
    }
    unsigned int idx = (unsigned int)k;
    sm_idx[t] = idx;
    out_idx[((size_t)pb << 6) + t] = (float)idx;
    unsigned int u = (unsigned int)(k >> 32);
    u = (u & 0x80000000u) ? (u & 0x7FFFFFFFu) : ~u;
    sm_loss[t] = (__uint_as_float(u) + sm_sx[t]) * (1.25f / 4194304.0f);
  }
  __syncthreads();

  float4* dst = (float4*)(out_q + (size_t)pb * 4096);
#pragma unroll
  for (int i = 0; i < 2; ++i) {
    int e4 = i * 512 + t;
    int p2 = e4 >> 4, d4 = e4 & 15;
    unsigned int idx = sm_idx[p2];
    dst[e4] = ((const float4*)(wT + (size_t)idx * DDIM))[d4];
  }

  if (t < 64) {
    float s = sm_loss[t];
#pragma unroll
    for (int off = 32; off > 0; off >>= 1) s += __shfl_down(s, off);
    if (t == 0) atomicAdd(loss_out, s);
  }
}

extern "C" void kernel_launch(void* const* d_in, const int* in_sizes, int n_in,
                              void* d_out, int out_size, void* d_ws, size_t ws_size,
                              hipStream_t stream) {
  const float* x = (const float*)d_in[0];  // (64,32,32,64) fp32
  const float* w = (const float*)d_in[1];  // (64,512) fp32

  float* out_q = (float*)d_out;            // 4194304 floats
  float* out_idx = out_q + 4194304;        // 65536 floats (indices)
  float* loss_out = out_q + 4259840;       // 1 float

  char* ws = (char*)d_ws;
  if (ws_size >= 8980480) {
    bf16x8* xa1 = (bf16x8*)d_out;                    // quantized region,
    bf16x8* xa2 = (bf16x8*)((char*)d_out + 8388608); //  overwritten by gather
    bf16x8* xa3 = (bf16x8*)(ws);
    bf16x8* wbp = (bf16x8*)(ws + 8388608);
    float* wT = (float*)(ws + 8585216);
    float* xsq = (float*)(ws + 8716288);
    float* wsq = (float*)(ws + 8978432);
    vq_prep_m<<<1184, 256, 0, stream>>>(x, w, xa1, xa2, xa3, wbp, wT, wsq,
                                        xsq, loss_out);
    vq_mfma<<<512, 256, 0, stream>>>(xa1, xa2, xa3, wbp, wsq, xsq, out_idx,
                                     loss_out);
    vq_gather<<<4096, 256, 0, stream>>>(out_idx, wT, (float4*)out_q);
  } else {
    float* wT = (float*)(ws);
    float* wsq = (float*)(ws + 131072);
    vq_prep<<<128, 256, 0, stream>>>(w, wT, wsq, loss_out);
    vq_main<<<1024, 512, 0, stream>>>(x, w, wT, wsq, out_q, out_idx,
                                      loss_out);
  }
}

// Round 12
// 109.503 us; speedup vs baseline: 1.2006x; 1.0336x over previous
//
#include <hip/hip_runtime.h>
#include <stdint.h>

// VectorQuantizer on MI355X (gfx950), round 12: bf16x3 split MFMA, fused.
// R11 evidence: MFMA path correct (absmax at session floor); ~48us of the
// timed region is the harness's 268MB ws poison (fillBufferAligned), leaving
// ~62us of kernels vs a 12.4us MFMA floor. This round deletes the XA
// global round-trip (lanes read A-fragments straight from x and split3
// in-register; ||x||^2 via 2 shuffles) and fuses the quantized gather into
// the main epilogue (XA no longer parks in d_out). 2 kernels total.
// A/B/C fragment mappings identical to R11's bench-verified ones.

#define DDIM 64
#define KCODES 512

typedef __bf16 bf16x8 __attribute__((ext_vector_type(8)));
typedef float f32x4 __attribute__((ext_vector_type(4)));

// ws layout (bytes): WB @0 (3 x 65536 = 196608), wT @196608 (131072),
//                    wsq @327680 (2048) -> need 329728

__device__ __forceinline__ void split3(float f, __bf16& h1, __bf16& h2,
                                       __bf16& h3) {
  h1 = (__bf16)f;
  float r1 = f - (float)h1;   // exact (Sterbenz)
  h2 = (__bf16)r1;
  float r2 = r1 - (float)h2;  // exact
  h3 = (__bf16)r2;            // residual beyond h3 ~ 2^-27 |f|
}

__global__ void vq_prep_m(const float* __restrict__ w,
                          bf16x8* __restrict__ wb,   // [3][32*2*64]
                          float* __restrict__ wT, float* __restrict__ wsq,
                          float* __restrict__ loss_out) {
  const int b = blockIdx.x, t = threadIdx.x;
  if (b < 16) {
    // ---- w split -> B-fragment layout: chunk id c = (ctg*2+h)*64 + L ----
    const int c = b * 256 + t;                // 0..4095
    const int ctg = c >> 7;                   // 16-code tile 0..31
    const int h = (c >> 6) & 1;               // k-half
    const int L = c & 63, quad = L >> 4, col = L & 15;
    bf16x8 v1, v2, v3;
#pragma unroll
    for (int j = 0; j < 8; ++j) {
      // B[k=quad*8+32h+j][n=ctg*16+col]  (R11 bench-verified)
      float f = w[(quad * 8 + 32 * h + j) * KCODES + ctg * 16 + col];
      __bf16 h1, h2, h3; split3(f, h1, h2, h3);
      v1[j] = h1; v2[j] = h2; v3[j] = h3;
    }
    wb[c] = v1; wb[4096 + c] = v2; wb[8192 + c] = v3;
  } else {
    // ---- wT transpose + wsq + loss zero ----
    int g = (b - 16) * 256 + t;               // 0..32767 over D*K
    int d = g >> 9, k = g & 511;
    wT[k * DDIM + d] = w[g];
    if (g < KCODES) {
      float s = 0.f;
      for (int dd = 0; dd < DDIM; ++dd) {
        float tv = w[dd * KCODES + g];
        s = fmaf(tv, tv, s);
      }
      wsq[g] = s;
    }
    if (g == 0) *loss_out = 0.f;              // d_out is poisoned each launch
  }
}

__global__ __launch_bounds__(256, 2)
void vq_mfma(const float* __restrict__ x_in, const bf16x8* __restrict__ wb,
             const float* __restrict__ wsq, const float* __restrict__ wT,
             float* __restrict__ out_q, float* __restrict__ out_idx,
             float* __restrict__ loss_out) {
  __shared__ bf16x8 ldsb[3072];               // 48KB: one 128-code phase
  __shared__ unsigned long long sm_key[128];
  __shared__ float sm_xsq[128];
  __shared__ unsigned int sm_idx[128];
  __shared__ float sm_loss[128];

  const int t = threadIdx.x, b = blockIdx.x;  // 512 blocks, 128 pts each
  const int wv = t >> 6, L = t & 63, quad = L >> 4, col = L & 15;

  // ---- load A-fragments straight from x, split3 in-register ----
  // a[as][split][h]; lane holds A[m=col][k=quad*8+32h+j] of point
  // pt = b*128 + (wv*2+as)*16 + col   (R11 bench-verified A layout)
  bf16x8 a[2][3][2];
#pragma unroll
  for (int as = 0; as < 2; ++as) {
    const float* xr =
        x_in + ((size_t)b * 128 + (wv * 2 + as) * 16 + col) * DDIM + quad * 8;
    float ssq = 0.f;
#pragma unroll
    for (int h = 0; h < 2; ++h) {
      float4 p0 = *(const float4*)(xr + 32 * h);
      float4 p1 = *(const float4*)(xr + 32 * h + 4);
      float f[8] = {p0.x, p0.y, p0.z, p0.w, p1.x, p1.y, p1.z, p1.w};
      bf16x8 v1, v2, v3;
#pragma unroll
      for (int j = 0; j < 8; ++j) {
        ssq = fmaf(f[j], f[j], ssq);
        __bf16 h1, h2, h3; split3(f[j], h1, h2, h3);
        v1[j] = h1; v2[j] = h2; v3[j] = h3;
      }
      a[as][0][h] = v1; a[as][1][h] = v2; a[as][2][h] = v3;
    }
    // combine the 4 quads (lanes col, col+16, col+32, col+48 = same point)
    ssq += __shfl_xor(ssq, 16, 64);
    ssq += __shfl_xor(ssq, 32, 64);
    if (quad == 0) sm_xsq[wv * 32 + as * 16 + col] = ssq;  // fp32-exact
  }

  float best[2][4];
  int bidx[2][4];
#pragma unroll
  for (int as = 0; as < 2; ++as)
#pragma unroll
    for (int r = 0; r < 4; ++r) { best[as][r] = 3.0e38f; bidx[as][r] = 0; }

#pragma unroll 1
  for (int ph = 0; ph < 4; ++ph) {
    __syncthreads();                          // prev compute / sm_xsq done
    // stage 48 chunks (ct,h,s) x 64 lanes of B-frags into LDS
#pragma unroll
    for (int i = 0; i < 12; ++i) {
      int idx = i * 256 + t;
      int chunk = idx >> 6, Ls = idx & 63;    // chunk = ct*6 + h*3 + s
      int ct = chunk / 6, r6 = chunk % 6;
      int h = r6 / 3, s = r6 % 3;
      ldsb[chunk * 64 + Ls] = wb[s * 4096 + ((ph * 8 + ct) * 2 + h) * 64 + Ls];
    }
    __syncthreads();
#pragma unroll 1
    for (int ct = 0; ct < 8; ++ct) {
      f32x4 acc0 = {0.f, 0.f, 0.f, 0.f};
      f32x4 acc1 = {0.f, 0.f, 0.f, 0.f};
#pragma unroll
      for (int h = 0; h < 2; ++h) {
        bf16x8 b0 = ldsb[(ct * 6 + h * 3 + 0) * 64 + L];
        bf16x8 b1 = ldsb[(ct * 6 + h * 3 + 1) * 64 + L];
        bf16x8 b2 = ldsb[(ct * 6 + h * 3 + 2) * 64 + L];
        // 6-term split (x1w1,x1w2,x2w1,x2w2,x1w3,x3w1), one fp32 acc
        acc0 = __builtin_amdgcn_mfma_f32_16x16x32_bf16(a[0][0][h], b0, acc0, 0, 0, 0);
        acc1 = __builtin_amdgcn_mfma_f32_16x16x32_bf16(a[1][0][h], b0, acc1, 0, 0, 0);
        acc0 = __builtin_amdgcn_mfma_f32_16x16x32_bf16(a[0][0][h], b1, acc0, 0, 0, 0);
        acc1 = __builtin_amdgcn_mfma_f32_16x16x32_bf16(a[1][0][h], b1, acc1, 0, 0, 0);
        acc0 = __builtin_amdgcn_mfma_f32_16x16x32_bf16(a[0][1][h], b0, acc0, 0, 0, 0);
        acc1 = __builtin_amdgcn_mfma_f32_16x16x32_bf16(a[1][1][h], b0, acc1, 0, 0, 0);
        acc0 = __builtin_amdgcn_mfma_f32_16x16x32_bf16(a[0][1][h], b1, acc0, 0, 0, 0);
        acc1 = __builtin_amdgcn_mfma_f32_16x16x32_bf16(a[1][1][h], b1, acc1, 0, 0, 0);
        acc0 = __builtin_amdgcn_mfma_f32_16x16x32_bf16(a[0][0][h], b2, acc0, 0, 0, 0);
        acc1 = __builtin_amdgcn_mfma_f32_16x16x32_bf16(a[1][0][h], b2, acc1, 0, 0, 0);
        acc0 = __builtin_amdgcn_mfma_f32_16x16x32_bf16(a[0][2][h], b0, acc0, 0, 0, 0);
        acc1 = __builtin_amdgcn_mfma_f32_16x16x32_bf16(a[1][2][h], b0, acc1, 0, 0, 0);
      }
      // dist + per-lane argmin; C layout: pt = quad*4 + r, code = col
      int code = ph * 128 + ct * 16 + col;
      float wq = wsq[code];
#pragma unroll
      for (int r = 0; r < 4; ++r) {
        float d0 = fmaf(acc0[r], -2.0f, wq);
        if (d0 < best[0][r]) { best[0][r] = d0; bidx[0][r] = code; }
        float d1 = fmaf(acc1[r], -2.0f, wq);
        if (d1 < best[1][r]) { best[1][r] = d1; bidx[1][r] = code; }
      }
    }
  }

  // ---- cross-lane reduce over the 16 cols; idx in low bits -> lowest idx ----
#pragma unroll
  for (int as = 0; as < 2; ++as) {
#pragma unroll
    for (int r = 0; r < 4; ++r) {
      unsigned int ub = __float_as_uint(best[as][r]);
      ub = (ub & 0x80000000u) ? ~ub : (ub | 0x80000000u);
      unsigned long long key = ((unsigned long long)ub << 32) |
                               (unsigned long long)(unsigned int)bidx[as][r];
#pragma unroll
      for (int off = 1; off < 16; off <<= 1) {
        unsigned long long o = __shfl_xor(key, off, 64);
        key = o < key ? o : key;
      }
      if (col == 0)
        sm_key[wv * 32 + as * 16 + quad * 4 + r] = key;
    }
  }
  __syncthreads();

  if (t < 128) {
    unsigned long long k = sm_key[t];
    unsigned int idx = (unsigned int)k;
    sm_idx[t] = idx;
    out_idx[(size_t)b * 128 + t] = (float)idx;
    unsigned int u = (unsigned int)(k >> 32);
    u = (u & 0x80000000u) ? (u & 0x7FFFFFFFu) : ~u;
    // ||x-q||^2 = ||x||^2 + (||q||^2 - 2 x.q), pre-scaled by 1.25/(N*D)
    sm_loss[t] = (__uint_as_float(u) + sm_xsq[t]) * (1.25f / 4194304.0f);
  }
  __syncthreads();

  // ---- fused epilogue: gather code rows, coalesced 128x64 out tile ----
  float4* dst = (float4*)(out_q + (size_t)b * 8192);
#pragma unroll
  for (int i = 0; i < 8; ++i) {
    int e4 = i * 256 + t;
    int p2 = e4 >> 4, d4 = e4 & 15;
    unsigned int idx = sm_idx[p2];                            // LDS broadcast
    dst[e4] = ((const float4*)(wT + (size_t)idx * DDIM))[d4]; // L2-hot
  }

  if (t < 64) {
    float s = sm_loss[t] + sm_loss[t + 64];
#pragma unroll
    for (int off = 32; off > 0; off >>= 1) s += __shfl_down(s, off);
    if (t == 0) atomicAdd(loss_out, s);       // 512 adds total
  }
}

// ---------------- fallback (R9 kernels, proven) ----------------

__global__ void vq_prep(const float* __restrict__ w, float* __restrict__ wT,
                        float* __restrict__ wsq, float* __restrict__ loss_out) {
  int g = blockIdx.x * 256 + threadIdx.x;
  int d = g >> 9, k = g & 511;
  wT[k * DDIM + d] = w[g];
  if (g < KCODES) {
    float s = 0.f;
    for (int dd = 0; dd < DDIM; ++dd) {
      float t = w[dd * KCODES + g];
      s = fmaf(t, t, s);
    }
    wsq[g] = s;
  }
  if (g == 0) *loss_out = 0.f;
}

__global__ __launch_bounds__(512, 8)
void vq_main(const float* __restrict__ x_in, const float* __restrict__ w,
             const float* __restrict__ wT, const float* __restrict__ wsq,
             float* __restrict__ out_q, float* __restrict__ out_idx,
             float* __restrict__ loss_out) {
  __shared__ float xs[DDIM][65];
  __shared__ unsigned long long sm_key[8][64];
  __shared__ unsigned int sm_idx[64];
  __shared__ float sm_sx[64];
  __shared__ float sm_loss[64];

  const int t = threadIdx.x;
  const int pb = blockIdx.x;
  const int wv = __builtin_amdgcn_readfirstlane(t >> 6);
  const int lane = t & 63;

  {
    const float4* src = (const float4*)(x_in + (size_t)pb * 4096);
#pragma unroll
    for (int i = 0; i < 2; ++i) {
      int e4 = i * 512 + t;
      float4 v = src[e4];
      int e = e4 << 2;
      int pt = e >> 6, d = e & 63;
      xs[d][pt] = v.x; xs[d + 1][pt] = v.y;
      xs[d + 2][pt] = v.z; xs[d + 3][pt] = v.w;
    }
  }
  __syncthreads();

  const int kbase = wv << 6;
  float best = 3.0e38f;
  int bidx = 0;
  float sx = 0.f;

#pragma unroll 1
  for (int kb = 0; kb < 2; ++kb) {
    const int k0 = kbase + (kb << 5);
    const float* wp = w + k0;
    float acc[32];
#pragma unroll
    for (int c = 0; c < 32; ++c) acc[c] = 0.f;
#pragma unroll 1
    for (int d8 = 0; d8 < 8; ++d8) {
      float xv[8];
#pragma unroll
      for (int dd = 0; dd < 8; ++dd) xv[dd] = xs[(d8 << 3) + dd][lane];
      if (wv == 0 && kb == 0) {
#pragma unroll
        for (int dd = 0; dd < 8; ++dd) sx = fmaf(xv[dd], xv[dd], sx);
      }
#pragma unroll
      for (int dd = 0; dd < 8; ++dd) {
        const float* wd = wp + (((d8 << 3) + dd) << 9);
#pragma unroll
        for (int c = 0; c < 32; ++c) acc[c] = fmaf(wd[c], xv[dd], acc[c]);
      }
    }
#pragma unroll
    for (int c = 0; c < 32; ++c) {
      float dist = fmaf(acc[c], -2.0f, wsq[k0 + c]);
      if (dist < best) { best = dist; bidx = k0 + c; }
    }
  }

  unsigned int ub = __float_as_uint(best);
  ub = (ub & 0x80000000u) ? ~ub : (ub | 0x80000000u);
  sm_key[wv][lane] =
      ((unsigned long long)ub << 32) | (unsigned long long)(unsigned int)bidx;
  if (wv == 0) sm_sx[lane] = sx;
  __syncthreads();

  if (t < 64) {
    unsigned long long k = sm_key[0][t];
#pragma unroll
    for (int wi = 1; wi < 8; ++wi) {
      unsigned long long k2 = sm_key[wi][t];
      k = k2 < k ? k2 : k;
    }
    unsigned int idx = (unsigned int)k;
    sm_idx[t] = idx;
    out_idx[((size_t)pb << 6) + t] = (float)idx;
    unsigned int u = (unsigned int)(k >> 32);
    u = (u & 0x80000000u) ? (u & 0x7FFFFFFFu) : ~u;
    sm_loss[t] = (__uint_as_float(u) + sm_sx[t]) * (1.25f / 4194304.0f);
  }
  __syncthreads();

  float4* dst = (float4*)(out_q + (size_t)pb * 4096);
#pragma unroll
  for (int i = 0; i < 2; ++i) {
    int e4 = i * 512 + t;
    int p2 = e4 >> 4, d4 = e4 & 15;
    unsigned int idx = sm_idx[p2];
    dst[e4] = ((const float4*)(wT + (size_t)idx * DDIM))[d4];
  }

  if (t < 64) {
    float s = sm_loss[t];
#pragma unroll
    for (int off = 32; off > 0; off >>= 1) s += __shfl_down(s, off);
    if (t == 0) atomicAdd(loss_out, s);
  }
}

extern "C" void kernel_launch(void* const* d_in, const int* in_sizes, int n_in,
                              void* d_out, int out_size, void* d_ws, size_t ws_size,
                              hipStream_t stream) {
  const float* x = (const float*)d_in[0];  // (64,32,32,64) fp32
  const float* w = (const float*)d_in[1];  // (64,512) fp32

  float* out_q = (float*)d_out;            // 4194304 floats
  float* out_idx = out_q + 4194304;        // 65536 floats (indices)
  float* loss_out = out_q + 4259840;       // 1 float

  char* ws = (char*)d_ws;
  if (ws_size >= 329728) {
    bf16x8* wbp = (bf16x8*)(ws);
    float* wT = (float*)(ws + 196608);
    float* wsq = (float*)(ws + 327680);
    vq_prep_m<<<144, 256, 0, stream>>>(w, wbp, wT, wsq, loss_out);
    vq_mfma<<<512, 256, 0, stream>>>(x, wbp, wsq, wT, out_q, out_idx,
                                     loss_out);
  } else {
    float* wT = (float*)(ws);
    float* wsq = (float*)(ws + 131072);
    vq_prep<<<128, 256, 0, stream>>>(w, wT, wsq, loss_out);
    vq_main<<<1024, 512, 0, stream>>>(x, w, wT, wsq, out_q, out_idx,
                                      loss_out);
  }
}